// Round 11
// baseline (378.006 us; speedup 1.0000x reference)
//
#include <hip/hip_runtime.h>

// Problem constants (fixed by the reference)
constexpr int NN = 50000;   // nodes
constexpr int NE = 800000;  // edges
constexpr float EPS = 1e-5f;

constexpr int CAP     = 64;                       // fixed CSR capacity (P(deg>64) ~ 1e-19)
constexpr int WCONV_NB = (57344 + 255) / 256;     // 224
constexpr int GEMM1_NB = (NN + 63) / 64;          // 782

// Fused-prep, XCD-partitioned: groups of 48 blocks (48 % 8 == 0 so
// bx%8 == l%8 == this block's XCD under round-robin dispatch).
//   l in [0,8):  role B, one gemm1 tile per XCD per group (balanced).
//   l in [8,48): role A, fill class c=l&7 (dst range c), rank=(l-8)>>3 in 0..4.
// Each class scans every edge chunk once, keeping only its dst range ->
// each csrf row written from ONE XCD -> lines merge in that L2.
constexpr int GROUPS   = 98;
constexpr int GSIZE    = 48;
constexpr int FUSED_NB = GROUPS * GSIZE;          // 4704
constexpr int ECHUNK   = 2048;
constexpr int NCHUNK   = (NE + ECHUNK - 1) / ECHUNK;  // 391
constexpr int DSTR     = NN / 8;                  // 6250

typedef short bf16x8 __attribute__((ext_vector_type(8)));
typedef float f32x4  __attribute__((ext_vector_type(4)));

// float -> bf16 bits (RNE, finite values)
__device__ __forceinline__ ushort f2bf(float x) {
    union { float f; unsigned u; } a; a.f = x;
    unsigned u = a.u;
    unsigned r = (u + 0x7FFFu + ((u >> 16) & 1u)) >> 16;
    return (ushort)r;
}
__device__ __forceinline__ float bflo(unsigned p) {
    union { unsigned u; float f; } a; a.u = p << 16; return a.f;
}
__device__ __forceinline__ float bfhi(unsigned p) {
    union { unsigned u; float f; } a; a.u = p & 0xFFFF0000u; return a.f;
}

// ---------------------------------------------------------------------------
// FUSED prep + layer-1 GEMM, XCD-partitioned fill.
// Role-A fill: class c writes only dst in [c*DSTR,(c+1)*DSTR) -> per-XCD
// 0.8 MB write window stays L2-resident, ~16 writes/row merge: csrf
// writeback ~47 MB -> ~6.4 MB. Coverage proof: cid = g + GROUPS*rank is
// injective per class and covers 0..489 >= NCHUNK-1; every (chunk,class)
// pair scanned exactly once; edge kept iff dst in class range -> every
// edge written exactly once REGARDLESS of the actual block->XCD mapping
// (mapping wrong => only the L2-merge speedup is lost).
// Role-B gemm1: verbatim round-8/9/10 (NTW=4), one tile per XCD per group.
// ---------------------------------------------------------------------------
__global__ __launch_bounds__(256, 3) void fused_prep_gemm1(
    const int* __restrict__ src, const int* __restrict__ dst,
    int* __restrict__ curA, int* __restrict__ curB,
    ushort* __restrict__ csrf,
    const float* __restrict__ W1, const float* __restrict__ W2,
    const float* __restrict__ W3, const float* __restrict__ W4,
    ushort* __restrict__ Wt,
    const float* __restrict__ X, ushort* __restrict__ U)
{
    constexpr int LDK = 136;
    __shared__ __align__(16) ushort Xs[64 * LDK];

    const int bx  = blockIdx.x;
    const int g   = bx / GSIZE;
    const int l   = bx - g * GSIZE;
    const int tid = threadIdx.x;

    if (l >= 8) {
        // ---------------- role A: XCD-partitioned fill / wconv ------------
        const int c    = l & 7;          // == bx % 8 == XCD class (48 % 8 == 0)
        const int rank = (l - 8) >> 3;   // 0..4
        const int cid  = g + GROUPS * rank;
        if (cid < NCHUNK) {
            const int lo = c * DSTR, hi = lo + DSTR;
            const int base = cid * ECHUNK;
#pragma unroll
            for (int i = 0; i < ECHUNK / 256; i++) {
                int e = base + i * 256 + tid;
                if (e < NE) {
                    int d = dst[e];
                    if (d >= lo && d < hi) {
                        if (e < NE / 2) {
                            int slot = atomicAdd(&curA[d], 1);
                            if (slot < CAP) csrf[(size_t)d * CAP + slot] = (ushort)src[e];
                        } else {
                            int old = atomicAdd(&curB[d], 1);
                            int slot = CAP - 1 - old;
                            if (slot >= 0) csrf[(size_t)d * CAP + slot] = (ushort)src[e];
                        }
                    }
                }
            }
        } else {
            // excess blocks (cid >= NCHUNK) -> wconv; wid injective:
            int wid = (cid - NCHUNK) * 8 + c;
            if (wid < WCONV_NB) {
                int id = wid * 256 + tid;
                if (id < 49152) {
                    int li = id / 16384, r = id % 16384;
                    int n = r >> 7, k = r & 127;
                    const float* W = (li == 0) ? W1 : (li == 1) ? W2 : W3;
                    Wt[li * 16384 + n * 128 + k] = f2bf(W[k * 128 + n]);
                } else if (id < 57344) {
                    int r = id - 49152;
                    int n = r >> 7, k = r & 127;
                    Wt[49152 + n * 128 + k] = f2bf(W4[k * 64 + n]);
                }
            }
        }
        return;
    }

    // ---------------- role B: gemm1 (F=128, no BN, NO dinv) ----------------
    int tile = g * 8 + l;
    if (tile >= GEMM1_NB) return;

    const int wave = tid >> 6;
    const int lane = tid & 63;
    const int m    = lane & 15;
    const int q    = lane >> 4;
    const int rowHalf = wave & 1;
    const int colHalf = wave >> 1;
    const int row0 = tile * 64;

    bf16x8 w[4][4];
#pragma unroll
    for (int nt = 0; nt < 4; nt++) {
#pragma unroll
        for (int ks = 0; ks < 4; ks++) {
            const float* wp = &W1[(ks * 32 + q * 8) * 128 + colHalf * 64 + nt * 16 + m];
            bf16x8 t;
#pragma unroll
            for (int j = 0; j < 8; j++) t[j] = (short)f2bf(wp[j * 128]);
            w[nt][ks] = t;
        }
    }

#pragma unroll
    for (int it = 0; it < 8; it++) {
        int idx = it * 256 + tid;
        int r   = idx >> 5;
        int c4  = (idx & 31) * 4;
        int row = row0 + r;
        float4 v = make_float4(0.f, 0.f, 0.f, 0.f);
        if (row < NN) v = *(const float4*)&X[(size_t)row * 128 + c4];
        ushort4 o;
        o.x = f2bf(v.x); o.y = f2bf(v.y); o.z = f2bf(v.z); o.w = f2bf(v.w);
        *(ushort4*)&Xs[r * LDK + c4] = o;
    }
    __syncthreads();

    f32x4 acc[2][4];
#pragma unroll
    for (int t = 0; t < 2; t++)
#pragma unroll
        for (int nt = 0; nt < 4; nt++) acc[t][nt] = (f32x4){0.f, 0.f, 0.f, 0.f};

#pragma unroll
    for (int ks = 0; ks < 4; ks++) {
        bf16x8 a0 = *(const bf16x8*)&Xs[(rowHalf * 32 + m)      * LDK + ks * 32 + q * 8];
        bf16x8 a1 = *(const bf16x8*)&Xs[(rowHalf * 32 + 16 + m) * LDK + ks * 32 + q * 8];
#pragma unroll
        for (int nt = 0; nt < 4; nt++) {
            acc[0][nt] = __builtin_amdgcn_mfma_f32_16x16x32_bf16(a0, w[nt][ks], acc[0][nt], 0, 0, 0);
            acc[1][nt] = __builtin_amdgcn_mfma_f32_16x16x32_bf16(a1, w[nt][ks], acc[1][nt], 0, 0, 0);
        }
    }

#pragma unroll
    for (int t = 0; t < 2; t++) {
#pragma unroll
        for (int r = 0; r < 4; r++) {
            int row = row0 + rowHalf * 32 + t * 16 + q * 4 + r;
            if (row < NN) {
#pragma unroll
                for (int nt = 0; nt < 4; nt++)
                    U[(size_t)row * 128 + colHalf * 64 + nt * 16 + m] = f2bf(acc[t][nt][r]);
            }
        }
    }
}

// ---------------------------------------------------------------------------
// MFMA GEMM (layers 2-4), VERBATIM round-4/8/9/10 (passing).
// ---------------------------------------------------------------------------
template<int F, bool BN>
__global__ __launch_bounds__(256, 3) void gemm_bf16_kernel(
    const void* __restrict__ Xv, const ushort* __restrict__ Wt,
    const int* __restrict__ curA, const int* __restrict__ curB,
    const float* __restrict__ sums, const float* __restrict__ sumsq,
    const float* __restrict__ g, const float* __restrict__ be,
    ushort* __restrict__ U)
{
    constexpr int NTW = F / 32;
    constexpr int LDK = 136;
    __shared__ __align__(16) ushort Xs[64 * LDK];
    __shared__ float scs[128], shs[128];

    const int tid  = threadIdx.x;
    const int wave = tid >> 6;
    const int lane = tid & 63;
    const int m    = lane & 15;
    const int q    = lane >> 4;
    const int rowHalf = wave & 1;
    const int colHalf = wave >> 1;
    const int row0 = blockIdx.x * 64;

    if constexpr (BN) {
        if (tid < 128) {
            float mu  = sums[tid] * (1.0f / NN);
            float var = sumsq[tid] * (1.0f / NN) - mu * mu;
            float scv = rsqrtf(var + EPS) * g[tid];
            scs[tid] = scv;
            shs[tid] = be[tid] - mu * scv;
        }
        __syncthreads();
    }

    bf16x8 w[NTW][4];
#pragma unroll
    for (int nt = 0; nt < NTW; nt++)
#pragma unroll
        for (int ks = 0; ks < 4; ks++)
            w[nt][ks] = *(const bf16x8*)&Wt[(colHalf * (F / 2) + nt * 16 + m) * 128 + ks * 32 + q * 8];

#pragma unroll
    for (int it = 0; it < 8; it++) {
        int idx = it * 256 + tid;
        int r   = idx >> 5;
        int c4  = (idx & 31) * 4;
        int row = row0 + r;
        float4 v = make_float4(0.f, 0.f, 0.f, 0.f);
        if constexpr (BN) {
            if (row < NN) {
                uint2 p = *(const uint2*)&((const ushort*)Xv)[(size_t)row * 128 + c4];
                v.x = bflo(p.x); v.y = bfhi(p.x);
                v.z = bflo(p.y); v.w = bfhi(p.y);
            }
            float4 s = *(const float4*)&scs[c4];
            float4 h = *(const float4*)&shs[c4];
            v.x = fmaxf(0.f, v.x * s.x + h.x);
            v.y = fmaxf(0.f, v.y * s.y + h.y);
            v.z = fmaxf(0.f, v.z * s.z + h.z);
            v.w = fmaxf(0.f, v.w * s.w + h.w);
        } else {
            if (row < NN) v = *(const float4*)&((const float*)Xv)[(size_t)row * 128 + c4];
        }
        ushort4 o;
        o.x = f2bf(v.x); o.y = f2bf(v.y); o.z = f2bf(v.z); o.w = f2bf(v.w);
        *(ushort4*)&Xs[r * LDK + c4] = o;
    }
    __syncthreads();

    f32x4 acc[2][NTW];
#pragma unroll
    for (int t = 0; t < 2; t++)
#pragma unroll
        for (int nt = 0; nt < NTW; nt++) acc[t][nt] = (f32x4){0.f, 0.f, 0.f, 0.f};

#pragma unroll
    for (int ks = 0; ks < 4; ks++) {
        bf16x8 a0 = *(const bf16x8*)&Xs[(rowHalf * 32 + m)      * LDK + ks * 32 + q * 8];
        bf16x8 a1 = *(const bf16x8*)&Xs[(rowHalf * 32 + 16 + m) * LDK + ks * 32 + q * 8];
#pragma unroll
        for (int nt = 0; nt < NTW; nt++) {
            acc[0][nt] = __builtin_amdgcn_mfma_f32_16x16x32_bf16(a0, w[nt][ks], acc[0][nt], 0, 0, 0);
            acc[1][nt] = __builtin_amdgcn_mfma_f32_16x16x32_bf16(a1, w[nt][ks], acc[1][nt], 0, 0, 0);
        }
    }

#pragma unroll
    for (int t = 0; t < 2; t++) {
#pragma unroll
        for (int r = 0; r < 4; r++) {
            int row = row0 + rowHalf * 32 + t * 16 + q * 4 + r;
            if (row < NN) {
                float di = rsqrtf((float)(curA[row] + curB[row]) + 1.0f);
#pragma unroll
                for (int nt = 0; nt < NTW; nt++) {
                    U[(size_t)row * F + colHalf * (F / 2) + nt * 16 + m] = f2bf(acc[t][nt][r] * di);
                }
            }
        }
    }
}

// ---------------------------------------------------------------------------
// Gather with virtual-index compaction. VERBATIM round-10 (passing).
// ---------------------------------------------------------------------------
template<bool SRCSCALE>
__global__ __launch_bounds__(256) void gather128_kernel(
    const ushort* __restrict__ csrf,
    const int* __restrict__ curA, const int* __restrict__ curB,
    const ushort* __restrict__ U, const float* __restrict__ b,
    ushort* __restrict__ Yb)
{
    int n    = (blockIdx.x * 256 + threadIdx.x) >> 6;
    int lane = threadIdx.x & 63;
    if (n >= NN) return;
    const int half = lane >> 5;
    const int c4   = (lane & 31) * 4;
    int dA = curA[n], dB = curB[n];
    int degRaw = dA + dB;
    int dA_c = min(dA, CAP);
    int dB_c = min(dB, CAP - dA_c);
    const int cnt = dA_c + dB_c;
    const int gap = CAP - cnt;
    int myIdx = (int)csrf[(size_t)n * CAP + lane];
    float myDs = 0.f;
    if constexpr (SRCSCALE) {
        int mi = min(myIdx, NN - 1);
        myDs = rsqrtf((float)(curA[mi] + curB[mi]) + 1.0f);
    }
    float a0 = 0.f, a1 = 0.f, a2 = 0.f, a3 = 0.f;

#define GSLOT(v) ((v) < dA_c ? (v) : (v) + gap)

    int j = 0;
    // ---- 16 neighbors / iter: 8 loads in flight per half
    for (; j + 16 <= cnt; j += 16) {
        int s0 = __shfl(myIdx, GSLOT(j + 0  + half));
        int s1 = __shfl(myIdx, GSLOT(j + 2  + half));
        int s2 = __shfl(myIdx, GSLOT(j + 4  + half));
        int s3 = __shfl(myIdx, GSLOT(j + 6  + half));
        int s4 = __shfl(myIdx, GSLOT(j + 8  + half));
        int s5 = __shfl(myIdx, GSLOT(j + 10 + half));
        int s6 = __shfl(myIdx, GSLOT(j + 12 + half));
        int s7 = __shfl(myIdx, GSLOT(j + 14 + half));
        uint2 u0 = *(const uint2*)&U[(size_t)s0 * 128 + c4];
        uint2 u1 = *(const uint2*)&U[(size_t)s1 * 128 + c4];
        uint2 u2 = *(const uint2*)&U[(size_t)s2 * 128 + c4];
        uint2 u3 = *(const uint2*)&U[(size_t)s3 * 128 + c4];
        uint2 u4 = *(const uint2*)&U[(size_t)s4 * 128 + c4];
        uint2 u5 = *(const uint2*)&U[(size_t)s5 * 128 + c4];
        uint2 u6 = *(const uint2*)&U[(size_t)s6 * 128 + c4];
        uint2 u7 = *(const uint2*)&U[(size_t)s7 * 128 + c4];
        if constexpr (SRCSCALE) {
            float c0 = __shfl(myDs, GSLOT(j + 0  + half));
            float c1 = __shfl(myDs, GSLOT(j + 2  + half));
            float c2 = __shfl(myDs, GSLOT(j + 4  + half));
            float c3 = __shfl(myDs, GSLOT(j + 6  + half));
            float c5 = __shfl(myDs, GSLOT(j + 10 + half));
            float c4s = __shfl(myDs, GSLOT(j + 8 + half));
            float c6 = __shfl(myDs, GSLOT(j + 12 + half));
            float c7 = __shfl(myDs, GSLOT(j + 14 + half));
            a0 += c0 * bflo(u0.x) + c1 * bflo(u1.x) + c2 * bflo(u2.x) + c3 * bflo(u3.x)
                + c4s * bflo(u4.x) + c5 * bflo(u5.x) + c6 * bflo(u6.x) + c7 * bflo(u7.x);
            a1 += c0 * bfhi(u0.x) + c1 * bfhi(u1.x) + c2 * bfhi(u2.x) + c3 * bfhi(u3.x)
                + c4s * bfhi(u4.x) + c5 * bfhi(u5.x) + c6 * bfhi(u6.x) + c7 * bfhi(u7.x);
            a2 += c0 * bflo(u0.y) + c1 * bflo(u1.y) + c2 * bflo(u2.y) + c3 * bflo(u3.y)
                + c4s * bflo(u4.y) + c5 * bflo(u5.y) + c6 * bflo(u6.y) + c7 * bflo(u7.y);
            a3 += c0 * bfhi(u0.y) + c1 * bfhi(u1.y) + c2 * bfhi(u2.y) + c3 * bfhi(u3.y)
                + c4s * bfhi(u4.y) + c5 * bfhi(u5.y) + c6 * bfhi(u6.y) + c7 * bfhi(u7.y);
        } else {
            a0 += bflo(u0.x) + bflo(u1.x) + bflo(u2.x) + bflo(u3.x)
                + bflo(u4.x) + bflo(u5.x) + bflo(u6.x) + bflo(u7.x);
            a1 += bfhi(u0.x) + bfhi(u1.x) + bfhi(u2.x) + bfhi(u3.x)
                + bfhi(u4.x) + bfhi(u5.x) + bfhi(u6.x) + bfhi(u7.x);
            a2 += bflo(u0.y) + bflo(u1.y) + bflo(u2.y) + bflo(u3.y)
                + bflo(u4.y) + bflo(u5.y) + bflo(u6.y) + bflo(u7.y);
            a3 += bfhi(u0.y) + bfhi(u1.y) + bfhi(u2.y) + bfhi(u3.y)
                + bfhi(u4.y) + bfhi(u5.y) + bfhi(u6.y) + bfhi(u7.y);
        }
    }
    // ---- 8 neighbors / iter: 4 loads in flight per half
    for (; j + 8 <= cnt; j += 8) {
        int s0 = __shfl(myIdx, GSLOT(j + 0 + half));
        int s1 = __shfl(myIdx, GSLOT(j + 2 + half));
        int s2 = __shfl(myIdx, GSLOT(j + 4 + half));
        int s3 = __shfl(myIdx, GSLOT(j + 6 + half));
        uint2 u0 = *(const uint2*)&U[(size_t)s0 * 128 + c4];
        uint2 u1 = *(const uint2*)&U[(size_t)s1 * 128 + c4];
        uint2 u2 = *(const uint2*)&U[(size_t)s2 * 128 + c4];
        uint2 u3 = *(const uint2*)&U[(size_t)s3 * 128 + c4];
        if constexpr (SRCSCALE) {
            float c0 = __shfl(myDs, GSLOT(j + 0 + half));
            float c1 = __shfl(myDs, GSLOT(j + 2 + half));
            float c2 = __shfl(myDs, GSLOT(j + 4 + half));
            float c3 = __shfl(myDs, GSLOT(j + 6 + half));
            a0 += c0 * bflo(u0.x) + c1 * bflo(u1.x) + c2 * bflo(u2.x) + c3 * bflo(u3.x);
            a1 += c0 * bfhi(u0.x) + c1 * bfhi(u1.x) + c2 * bfhi(u2.x) + c3 * bfhi(u3.x);
            a2 += c0 * bflo(u0.y) + c1 * bflo(u1.y) + c2 * bflo(u2.y) + c3 * bflo(u3.y);
            a3 += c0 * bfhi(u0.y) + c1 * bfhi(u1.y) + c2 * bfhi(u2.y) + c3 * bfhi(u3.y);
        } else {
            a0 += bflo(u0.x) + bflo(u1.x) + bflo(u2.x) + bflo(u3.x);
            a1 += bfhi(u0.x) + bfhi(u1.x) + bfhi(u2.x) + bfhi(u3.x);
            a2 += bflo(u0.y) + bflo(u1.y) + bflo(u2.y) + bflo(u3.y);
            a3 += bfhi(u0.y) + bfhi(u1.y) + bfhi(u2.y) + bfhi(u3.y);
        }
    }
    // ---- 4 neighbors / iter: 2 loads in flight per half
    for (; j + 4 <= cnt; j += 4) {
        int s0 = __shfl(myIdx, GSLOT(j + 0 + half));
        int s1 = __shfl(myIdx, GSLOT(j + 2 + half));
        uint2 u0 = *(const uint2*)&U[(size_t)s0 * 128 + c4];
        uint2 u1 = *(const uint2*)&U[(size_t)s1 * 128 + c4];
        if constexpr (SRCSCALE) {
            float c0 = __shfl(myDs, GSLOT(j + 0 + half));
            float c1 = __shfl(myDs, GSLOT(j + 2 + half));
            a0 += c0 * bflo(u0.x) + c1 * bflo(u1.x);
            a1 += c0 * bfhi(u0.x) + c1 * bfhi(u1.x);
            a2 += c0 * bflo(u0.y) + c1 * bflo(u1.y);
            a3 += c0 * bfhi(u0.y) + c1 * bfhi(u1.y);
        } else {
            a0 += bflo(u0.x) + bflo(u1.x);
            a1 += bfhi(u0.x) + bfhi(u1.x);
            a2 += bflo(u0.y) + bflo(u1.y);
            a3 += bfhi(u0.y) + bfhi(u1.y);
        }
    }
    // ---- tail: 1..3 neighbors left (convergent clamped shuffle)
    for (; j < cnt; j += 2) {
        int jj = j + half;
        int vv = min(jj, cnt - 1);
        int sl = GSLOT(vv);
        int s  = __shfl(myIdx, sl);
        float sc = 1.f;
        if constexpr (SRCSCALE) sc = __shfl(myDs, sl);
        uint2 u = *(const uint2*)&U[(size_t)s * 128 + c4];
        if (jj < cnt) {
            a0 += sc * bflo(u.x); a1 += sc * bfhi(u.x);
            a2 += sc * bflo(u.y); a3 += sc * bfhi(u.y);
        }
    }
#undef GSLOT

    a0 += __shfl_xor(a0, 32);
    a1 += __shfl_xor(a1, 32);
    a2 += __shfl_xor(a2, 32);
    a3 += __shfl_xor(a3, 32);

    uint2 us = *(const uint2*)&U[(size_t)n * 128 + c4];
    float di = rsqrtf((float)degRaw + 1.0f);
    float selfs = SRCSCALE ? di : 1.0f;
    float4 bb = *(const float4*)&b[c4];
    float o0 = di * (a0 + selfs * bflo(us.x)) + bb.x;
    float o1 = di * (a1 + selfs * bfhi(us.x)) + bb.y;
    float o2 = di * (a2 + selfs * bflo(us.y)) + bb.z;
    float o3 = di * (a3 + selfs * bfhi(us.y)) + bb.w;
    if (half == 0) {
        ushort4 o;
        o.x = f2bf(o0); o.y = f2bf(o1); o.z = f2bf(o2); o.w = f2bf(o3);
        *(ushort4*)&Yb[(size_t)n * 128 + c4] = o;
    }
}

// ---------------------------------------------------------------------------
// gather64 with virtual compaction. VERBATIM round-10 (passing).
// ---------------------------------------------------------------------------
__global__ __launch_bounds__(256) void gather64_kernel(
    const ushort* __restrict__ csrf,
    const int* __restrict__ curA, const int* __restrict__ curB,
    const ushort* __restrict__ U, const float* __restrict__ b,
    float* __restrict__ Y)
{
    int t  = blockIdx.x * 256 + threadIdx.x;
    int n  = t >> 5;
    int l2 = t & 31;
    if (n >= NN) return;
    const int coff = l2 * 2;
    int dA = curA[n], dB = curB[n];
    int degRaw = dA + dB;
    int dA_c = min(dA, CAP);
    int dB_c = min(dB, CAP - dA_c);
    const int cnt = dA_c + dB_c;
    const int gap = CAP - cnt;
    int iA = (int)csrf[(size_t)n * CAP + l2];
    int iB = (int)csrf[(size_t)n * CAP + 32 + l2];
    float ax = 0.f, ay = 0.f;

#define GIDX(v, sv)                                            \
    int sv;                                                    \
    {                                                          \
        int _s = ((v) < dA_c) ? (v) : (v) + gap;               \
        int _l = __shfl(iA, _s & 31, 32);                      \
        int _h = __shfl(iB, _s & 31, 32);                      \
        sv = (_s < 32) ? _l : _h;                              \
    }

    int j = 0;
    for (; j + 8 <= cnt; j += 8) {
        GIDX(j + 0, s0) GIDX(j + 1, s1) GIDX(j + 2, s2) GIDX(j + 3, s3)
        GIDX(j + 4, s4) GIDX(j + 5, s5) GIDX(j + 6, s6) GIDX(j + 7, s7)
        unsigned u0 = *(const unsigned*)&U[(size_t)s0 * 64 + coff];
        unsigned u1 = *(const unsigned*)&U[(size_t)s1 * 64 + coff];
        unsigned u2 = *(const unsigned*)&U[(size_t)s2 * 64 + coff];
        unsigned u3 = *(const unsigned*)&U[(size_t)s3 * 64 + coff];
        unsigned u4 = *(const unsigned*)&U[(size_t)s4 * 64 + coff];
        unsigned u5 = *(const unsigned*)&U[(size_t)s5 * 64 + coff];
        unsigned u6 = *(const unsigned*)&U[(size_t)s6 * 64 + coff];
        unsigned u7 = *(const unsigned*)&U[(size_t)s7 * 64 + coff];
        ax += bflo(u0) + bflo(u1) + bflo(u2) + bflo(u3)
            + bflo(u4) + bflo(u5) + bflo(u6) + bflo(u7);
        ay += bfhi(u0) + bfhi(u1) + bfhi(u2) + bfhi(u3)
            + bfhi(u4) + bfhi(u5) + bfhi(u6) + bfhi(u7);
    }
    for (; j + 4 <= cnt; j += 4) {
        GIDX(j + 0, s0) GIDX(j + 1, s1) GIDX(j + 2, s2) GIDX(j + 3, s3)
        unsigned u0 = *(const unsigned*)&U[(size_t)s0 * 64 + coff];
        unsigned u1 = *(const unsigned*)&U[(size_t)s1 * 64 + coff];
        unsigned u2 = *(const unsigned*)&U[(size_t)s2 * 64 + coff];
        unsigned u3 = *(const unsigned*)&U[(size_t)s3 * 64 + coff];
        ax += bflo(u0) + bflo(u1) + bflo(u2) + bflo(u3);
        ay += bfhi(u0) + bfhi(u1) + bfhi(u2) + bfhi(u3);
    }
    for (; j < cnt; j++) {
        GIDX(j, s)
        unsigned u = *(const unsigned*)&U[(size_t)s * 64 + coff];
        ax += bflo(u); ay += bfhi(u);
    }
#undef GIDX

    unsigned us = *(const unsigned*)&U[(size_t)n * 64 + coff];
    float di = rsqrtf((float)degRaw + 1.0f);
    float ox = di * (ax + bflo(us)) + b[coff];
    float oy = di * (ay + bfhi(us)) + b[coff + 1];
    *(float2*)&Y[(size_t)n * 64 + coff] = make_float2(ox, oy);
}

// ---------------------------------------------------------------------------
// BN stats (read-only), VERBATIM round-4/8/9/10 (passing).
// ---------------------------------------------------------------------------
__global__ __launch_bounds__(256) void stats_kernel(const ushort* __restrict__ Yb,
                                                    float* __restrict__ sums,
                                                    float* __restrict__ sumsq)
{
    __shared__ float ssum[128], ssq[128];
    if (threadIdx.x < 128) { ssum[threadIdx.x] = 0.f; ssq[threadIdx.x] = 0.f; }
    __syncthreads();

    const int lane   = threadIdx.x & 63;
    const int gwave  = (blockIdx.x * 256 + threadIdx.x) >> 6;
    const int nWaves = gridDim.x * 4;
    const int coff   = lane * 2;

    float s0 = 0.f, s1 = 0.f, q0 = 0.f, q1 = 0.f;
    for (int row = gwave; row < NN; row += nWaves) {
        unsigned p = *(const unsigned*)&Yb[(size_t)row * 128 + coff];
        float yx = bflo(p), yy = bfhi(p);
        s0 += yx; q0 += yx * yx;
        s1 += yy; q1 += yy * yy;
    }
    atomicAdd(&ssum[coff], s0);     atomicAdd(&ssum[coff + 1], s1);
    atomicAdd(&ssq[coff], q0);      atomicAdd(&ssq[coff + 1], q1);
    __syncthreads();
    if (threadIdx.x < 128) {
        atomicAdd(&sums[threadIdx.x],  ssum[threadIdx.x]);
        atomicAdd(&sumsq[threadIdx.x], ssq[threadIdx.x]);
    }
}

// ---------------------------------------------------------------------------
extern "C" void kernel_launch(void* const* d_in, const int* in_sizes, int n_in,
                              void* d_out, int out_size, void* d_ws, size_t ws_size,
                              hipStream_t stream)
{
    const float* x   = (const float*)d_in[0];
    const int*   ei  = (const int*)d_in[1];
    const int*   src = ei;
    const int*   dst = ei + NE;
    const float* W1 = (const float*)d_in[2];  const float* b1 = (const float*)d_in[3];
    const float* W2 = (const float*)d_in[4];  const float* b2 = (const float*)d_in[5];
    const float* W3 = (const float*)d_in[6];  const float* b3 = (const float*)d_in[7];
    const float* W4 = (const float*)d_in[8];  const float* b4 = (const float*)d_in[9];
    const float* g1 = (const float*)d_in[10]; const float* be1 = (const float*)d_in[11];
    const float* g2 = (const float*)d_in[12]; const float* be2 = (const float*)d_in[13];
    const float* g3 = (const float*)d_in[14]; const float* be3 = (const float*)d_in[15];
    float* out = (float*)d_out;

    // workspace layout — BYTE-IDENTICAL to round-0/4/8/9/10 (FROZEN).
    char* wsb = (char*)d_ws;
    int*   curA   = (int*)wsb;                      // NN i
    int*   curB   = curA + NN;                      // NN i
    float* stats  = (float*)(curB + NN);            // 3 layers x 256 f
    ushort* Wt    = (ushort*)(stats + 768);         // 57344 us
    ushort* csrf  = Wt + 57344;                     // NN*64 us (6.4 MB)
    ushort* Yb    = csrf + (size_t)NN * CAP;        // NN*128 us (bf16 Y)
    ushort* U     = Yb + (size_t)NN * 128;          // NN*128 us (bf16 U)

    float* sums1 = stats;       float* sumsq1 = stats + 128;
    float* sums2 = stats + 256; float* sumsq2 = stats + 384;
    float* sums3 = stats + 512; float* sumsq3 = stats + 640;

    const ushort* Wt2 = Wt + 16384;
    const ushort* Wt3 = Wt + 32768;
    const ushort* Wt4 = Wt + 49152;

    const int gemmGrid   = (NN + 63) / 64;           // 782
    const int gathGrid   = (NN * 64 + 255) / 256;    // one wave per node
    const int gath64Grid = (NN * 32 + 255) / 256;    // half-wave per node

    // ---- prep + layer-1 GEMM fused (XCD-partitioned CSR fill)
    hipMemsetAsync(curA, 0, 2 * NN * sizeof(int) + 768 * sizeof(float), stream);
    fused_prep_gemm1<<<FUSED_NB, 256, 0, stream>>>(src, dst, curA, curB, csrf,
                                                   W1, W2, W3, W4, Wt, x, U);

    // ---- Layer 1 (U unscaled -> gather applies dinv[src] per neighbor)
    gather128_kernel<true><<<gathGrid, 256, 0, stream>>>(csrf, curA, curB, U, b1, Yb);
    stats_kernel<<<512, 256, 0, stream>>>(Yb, sums1, sumsq1);

    // ---- Layer 2
    gemm_bf16_kernel<128, true><<<gemmGrid, 256, 0, stream>>>(Yb, Wt2, curA, curB, sums1, sumsq1, g1, be1, U);
    gather128_kernel<false><<<gathGrid, 256, 0, stream>>>(csrf, curA, curB, U, b2, Yb);
    stats_kernel<<<512, 256, 0, stream>>>(Yb, sums2, sumsq2);

    // ---- Layer 3
    gemm_bf16_kernel<128, true><<<gemmGrid, 256, 0, stream>>>(Yb, Wt3, curA, curB, sums2, sumsq2, g2, be2, U);
    gather128_kernel<false><<<gathGrid, 256, 0, stream>>>(csrf, curA, curB, U, b3, Yb);
    stats_kernel<<<512, 256, 0, stream>>>(Yb, sums3, sumsq3);

    // ---- Layer 4 (no BN stats; gather straight to d_out)
    gemm_bf16_kernel<64, true><<<gemmGrid, 256, 0, stream>>>(Yb, Wt4, curA, curB, sums3, sumsq3, g3, be3, U);
    gather64_kernel<<<gath64Grid, 256, 0, stream>>>(csrf, curA, curB, U, b4, out);
}

// Round 12
// 358.751 us; speedup vs baseline: 1.0537x; 1.0537x over previous
//
#include <hip/hip_runtime.h>

// Problem constants (fixed by the reference)
constexpr int NN = 50000;   // nodes
constexpr int NE = 800000;  // edges
constexpr float EPS = 1e-5f;

constexpr int CAP     = 64;                       // fixed CSR capacity (P(deg>64) ~ 1e-19)
constexpr int FILL_NB = (NE + 255) / 256;         // 3125
constexpr int WCONV_NB = (57344 + 255) / 256;     // 224
constexpr int GEMM1_NB = (NN + 63) / 64;          // 782

// Fused-prep interleave (ROUND-10 REVERT): groups of 21 = 4 gemm1 + 17 fill.
// Round-11's XCD-partitioned fill REGRESSED: write-merge saved only 12 MB
// (csrf lines evicted by streaming traffic before all ~16 touches) while the
// 8x dst re-scan added 21 MB of reads -> net hbm_bytes 80->90 MB, 52->70 us.
constexpr int GROUPS   = 197;
constexpr int FUSED_NB = GROUPS * 21;             // 4137

typedef short bf16x8 __attribute__((ext_vector_type(8)));
typedef float f32x4  __attribute__((ext_vector_type(4)));

// float -> bf16 bits (RNE, finite values)
__device__ __forceinline__ ushort f2bf(float x) {
    union { float f; unsigned u; } a; a.f = x;
    unsigned u = a.u;
    unsigned r = (u + 0x7FFFu + ((u >> 16) & 1u)) >> 16;
    return (ushort)r;
}
__device__ __forceinline__ float bflo(unsigned p) {
    union { unsigned u; float f; } a; a.u = p << 16; return a.f;
}
__device__ __forceinline__ float bfhi(unsigned p) {
    union { unsigned u; float f; } a; a.u = p & 0xFFFF0000u; return a.f;
}

// ---------------------------------------------------------------------------
// FUSED prep + layer-1 GEMM. VERBATIM round-8/9/10 (passing, 52 us).
// ---------------------------------------------------------------------------
__global__ __launch_bounds__(256, 3) void fused_prep_gemm1(
    const int* __restrict__ src, const int* __restrict__ dst,
    int* __restrict__ curA, int* __restrict__ curB,
    ushort* __restrict__ csrf,
    const float* __restrict__ W1, const float* __restrict__ W2,
    const float* __restrict__ W3, const float* __restrict__ W4,
    ushort* __restrict__ Wt,
    const float* __restrict__ X, ushort* __restrict__ U)
{
    constexpr int LDK = 136;
    __shared__ __align__(16) ushort Xs[64 * LDK];

    const int bx  = blockIdx.x;
    const int g   = bx / 21;
    const int l   = bx - g * 21;
    const int tid = threadIdx.x;

    if (l >= 4) {
        // ---------------- role A: fill / wconv ----------------
        int fid = g * 17 + (l - 4);              // 0..3348
        if (fid < FILL_NB) {
            int e = fid * 256 + tid;
            if (e < NE) {
                int d = dst[e];
                if (e < NE / 2) {
                    int slot = atomicAdd(&curA[d], 1);
                    if (slot < CAP) csrf[(size_t)d * CAP + slot] = (ushort)src[e];
                } else {
                    int old = atomicAdd(&curB[d], 1);
                    int slot = CAP - 1 - old;
                    if (slot >= 0) csrf[(size_t)d * CAP + slot] = (ushort)src[e];
                }
            }
        } else {
            int id = (fid - FILL_NB) * 256 + tid;
            if (id < 49152) {
                int li = id / 16384, r = id % 16384;
                int n = r >> 7, k = r & 127;
                const float* W = (li == 0) ? W1 : (li == 1) ? W2 : W3;
                Wt[li * 16384 + n * 128 + k] = f2bf(W[k * 128 + n]);
            } else if (id < 57344) {
                int r = id - 49152;
                int n = r >> 7, k = r & 127;
                Wt[49152 + n * 128 + k] = f2bf(W4[k * 64 + n]);
            }
        }
        return;
    }

    // ---------------- role B: gemm1 (F=128, no BN, NO dinv) ----------------
    int tile = g * 4 + l;
    if (tile >= GEMM1_NB) return;

    const int wave = tid >> 6;
    const int lane = tid & 63;
    const int m    = lane & 15;
    const int q    = lane >> 4;
    const int rowHalf = wave & 1;
    const int colHalf = wave >> 1;
    const int row0 = tile * 64;

    bf16x8 w[4][4];
#pragma unroll
    for (int nt = 0; nt < 4; nt++) {
#pragma unroll
        for (int ks = 0; ks < 4; ks++) {
            const float* wp = &W1[(ks * 32 + q * 8) * 128 + colHalf * 64 + nt * 16 + m];
            bf16x8 t;
#pragma unroll
            for (int j = 0; j < 8; j++) t[j] = (short)f2bf(wp[j * 128]);
            w[nt][ks] = t;
        }
    }

#pragma unroll
    for (int it = 0; it < 8; it++) {
        int idx = it * 256 + tid;
        int r   = idx >> 5;
        int c4  = (idx & 31) * 4;
        int row = row0 + r;
        float4 v = make_float4(0.f, 0.f, 0.f, 0.f);
        if (row < NN) v = *(const float4*)&X[(size_t)row * 128 + c4];
        ushort4 o;
        o.x = f2bf(v.x); o.y = f2bf(v.y); o.z = f2bf(v.z); o.w = f2bf(v.w);
        *(ushort4*)&Xs[r * LDK + c4] = o;
    }
    __syncthreads();

    f32x4 acc[2][4];
#pragma unroll
    for (int t = 0; t < 2; t++)
#pragma unroll
        for (int nt = 0; nt < 4; nt++) acc[t][nt] = (f32x4){0.f, 0.f, 0.f, 0.f};

#pragma unroll
    for (int ks = 0; ks < 4; ks++) {
        bf16x8 a0 = *(const bf16x8*)&Xs[(rowHalf * 32 + m)      * LDK + ks * 32 + q * 8];
        bf16x8 a1 = *(const bf16x8*)&Xs[(rowHalf * 32 + 16 + m) * LDK + ks * 32 + q * 8];
#pragma unroll
        for (int nt = 0; nt < 4; nt++) {
            acc[0][nt] = __builtin_amdgcn_mfma_f32_16x16x32_bf16(a0, w[nt][ks], acc[0][nt], 0, 0, 0);
            acc[1][nt] = __builtin_amdgcn_mfma_f32_16x16x32_bf16(a1, w[nt][ks], acc[1][nt], 0, 0, 0);
        }
    }

#pragma unroll
    for (int t = 0; t < 2; t++) {
#pragma unroll
        for (int r = 0; r < 4; r++) {
            int row = row0 + rowHalf * 32 + t * 16 + q * 4 + r;
            if (row < NN) {
#pragma unroll
                for (int nt = 0; nt < 4; nt++)
                    U[(size_t)row * 128 + colHalf * 64 + nt * 16 + m] = f2bf(acc[t][nt][r]);
            }
        }
    }
}

// ---------------------------------------------------------------------------
// MFMA GEMM (layers 2-4), VERBATIM round-4/8/9/10 (passing).
// ---------------------------------------------------------------------------
template<int F, bool BN>
__global__ __launch_bounds__(256, 3) void gemm_bf16_kernel(
    const void* __restrict__ Xv, const ushort* __restrict__ Wt,
    const int* __restrict__ curA, const int* __restrict__ curB,
    const float* __restrict__ sums, const float* __restrict__ sumsq,
    const float* __restrict__ g, const float* __restrict__ be,
    ushort* __restrict__ U)
{
    constexpr int NTW = F / 32;
    constexpr int LDK = 136;
    __shared__ __align__(16) ushort Xs[64 * LDK];
    __shared__ float scs[128], shs[128];

    const int tid  = threadIdx.x;
    const int wave = tid >> 6;
    const int lane = tid & 63;
    const int m    = lane & 15;
    const int q    = lane >> 4;
    const int rowHalf = wave & 1;
    const int colHalf = wave >> 1;
    const int row0 = blockIdx.x * 64;

    if constexpr (BN) {
        if (tid < 128) {
            float mu  = sums[tid] * (1.0f / NN);
            float var = sumsq[tid] * (1.0f / NN) - mu * mu;
            float scv = rsqrtf(var + EPS) * g[tid];
            scs[tid] = scv;
            shs[tid] = be[tid] - mu * scv;
        }
        __syncthreads();
    }

    bf16x8 w[NTW][4];
#pragma unroll
    for (int nt = 0; nt < NTW; nt++)
#pragma unroll
        for (int ks = 0; ks < 4; ks++)
            w[nt][ks] = *(const bf16x8*)&Wt[(colHalf * (F / 2) + nt * 16 + m) * 128 + ks * 32 + q * 8];

#pragma unroll
    for (int it = 0; it < 8; it++) {
        int idx = it * 256 + tid;
        int r   = idx >> 5;
        int c4  = (idx & 31) * 4;
        int row = row0 + r;
        float4 v = make_float4(0.f, 0.f, 0.f, 0.f);
        if constexpr (BN) {
            if (row < NN) {
                uint2 p = *(const uint2*)&((const ushort*)Xv)[(size_t)row * 128 + c4];
                v.x = bflo(p.x); v.y = bfhi(p.x);
                v.z = bflo(p.y); v.w = bfhi(p.y);
            }
            float4 s = *(const float4*)&scs[c4];
            float4 h = *(const float4*)&shs[c4];
            v.x = fmaxf(0.f, v.x * s.x + h.x);
            v.y = fmaxf(0.f, v.y * s.y + h.y);
            v.z = fmaxf(0.f, v.z * s.z + h.z);
            v.w = fmaxf(0.f, v.w * s.w + h.w);
        } else {
            if (row < NN) v = *(const float4*)&((const float*)Xv)[(size_t)row * 128 + c4];
        }
        ushort4 o;
        o.x = f2bf(v.x); o.y = f2bf(v.y); o.z = f2bf(v.z); o.w = f2bf(v.w);
        *(ushort4*)&Xs[r * LDK + c4] = o;
    }
    __syncthreads();

    f32x4 acc[2][NTW];
#pragma unroll
    for (int t = 0; t < 2; t++)
#pragma unroll
        for (int nt = 0; nt < NTW; nt++) acc[t][nt] = (f32x4){0.f, 0.f, 0.f, 0.f};

#pragma unroll
    for (int ks = 0; ks < 4; ks++) {
        bf16x8 a0 = *(const bf16x8*)&Xs[(rowHalf * 32 + m)      * LDK + ks * 32 + q * 8];
        bf16x8 a1 = *(const bf16x8*)&Xs[(rowHalf * 32 + 16 + m) * LDK + ks * 32 + q * 8];
#pragma unroll
        for (int nt = 0; nt < NTW; nt++) {
            acc[0][nt] = __builtin_amdgcn_mfma_f32_16x16x32_bf16(a0, w[nt][ks], acc[0][nt], 0, 0, 0);
            acc[1][nt] = __builtin_amdgcn_mfma_f32_16x16x32_bf16(a1, w[nt][ks], acc[1][nt], 0, 0, 0);
        }
    }

#pragma unroll
    for (int t = 0; t < 2; t++) {
#pragma unroll
        for (int r = 0; r < 4; r++) {
            int row = row0 + rowHalf * 32 + t * 16 + q * 4 + r;
            if (row < NN) {
                float di = rsqrtf((float)(curA[row] + curB[row]) + 1.0f);
#pragma unroll
                for (int nt = 0; nt < NTW; nt++) {
                    U[(size_t)row * F + colHalf * (F / 2) + nt * 16 + m] = f2bf(acc[t][nt][r] * di);
                }
            }
        }
    }
}

// ---------------------------------------------------------------------------
// Gather with virtual-index compaction. VERBATIM round-10 (passing).
// ---------------------------------------------------------------------------
template<bool SRCSCALE>
__global__ __launch_bounds__(256) void gather128_kernel(
    const ushort* __restrict__ csrf,
    const int* __restrict__ curA, const int* __restrict__ curB,
    const ushort* __restrict__ U, const float* __restrict__ b,
    ushort* __restrict__ Yb)
{
    int n    = (blockIdx.x * 256 + threadIdx.x) >> 6;
    int lane = threadIdx.x & 63;
    if (n >= NN) return;
    const int half = lane >> 5;
    const int c4   = (lane & 31) * 4;
    int dA = curA[n], dB = curB[n];
    int degRaw = dA + dB;
    int dA_c = min(dA, CAP);
    int dB_c = min(dB, CAP - dA_c);
    const int cnt = dA_c + dB_c;
    const int gap = CAP - cnt;
    int myIdx = (int)csrf[(size_t)n * CAP + lane];
    float myDs = 0.f;
    if constexpr (SRCSCALE) {
        int mi = min(myIdx, NN - 1);
        myDs = rsqrtf((float)(curA[mi] + curB[mi]) + 1.0f);
    }
    float a0 = 0.f, a1 = 0.f, a2 = 0.f, a3 = 0.f;

#define GSLOT(v) ((v) < dA_c ? (v) : (v) + gap)

    int j = 0;
    // ---- 16 neighbors / iter: 8 loads in flight per half
    for (; j + 16 <= cnt; j += 16) {
        int s0 = __shfl(myIdx, GSLOT(j + 0  + half));
        int s1 = __shfl(myIdx, GSLOT(j + 2  + half));
        int s2 = __shfl(myIdx, GSLOT(j + 4  + half));
        int s3 = __shfl(myIdx, GSLOT(j + 6  + half));
        int s4 = __shfl(myIdx, GSLOT(j + 8  + half));
        int s5 = __shfl(myIdx, GSLOT(j + 10 + half));
        int s6 = __shfl(myIdx, GSLOT(j + 12 + half));
        int s7 = __shfl(myIdx, GSLOT(j + 14 + half));
        uint2 u0 = *(const uint2*)&U[(size_t)s0 * 128 + c4];
        uint2 u1 = *(const uint2*)&U[(size_t)s1 * 128 + c4];
        uint2 u2 = *(const uint2*)&U[(size_t)s2 * 128 + c4];
        uint2 u3 = *(const uint2*)&U[(size_t)s3 * 128 + c4];
        uint2 u4 = *(const uint2*)&U[(size_t)s4 * 128 + c4];
        uint2 u5 = *(const uint2*)&U[(size_t)s5 * 128 + c4];
        uint2 u6 = *(const uint2*)&U[(size_t)s6 * 128 + c4];
        uint2 u7 = *(const uint2*)&U[(size_t)s7 * 128 + c4];
        if constexpr (SRCSCALE) {
            float c0 = __shfl(myDs, GSLOT(j + 0  + half));
            float c1 = __shfl(myDs, GSLOT(j + 2  + half));
            float c2 = __shfl(myDs, GSLOT(j + 4  + half));
            float c3 = __shfl(myDs, GSLOT(j + 6  + half));
            float c5 = __shfl(myDs, GSLOT(j + 10 + half));
            float c4s = __shfl(myDs, GSLOT(j + 8 + half));
            float c6 = __shfl(myDs, GSLOT(j + 12 + half));
            float c7 = __shfl(myDs, GSLOT(j + 14 + half));
            a0 += c0 * bflo(u0.x) + c1 * bflo(u1.x) + c2 * bflo(u2.x) + c3 * bflo(u3.x)
                + c4s * bflo(u4.x) + c5 * bflo(u5.x) + c6 * bflo(u6.x) + c7 * bflo(u7.x);
            a1 += c0 * bfhi(u0.x) + c1 * bfhi(u1.x) + c2 * bfhi(u2.x) + c3 * bfhi(u3.x)
                + c4s * bfhi(u4.x) + c5 * bfhi(u5.x) + c6 * bfhi(u6.x) + c7 * bfhi(u7.x);
            a2 += c0 * bflo(u0.y) + c1 * bflo(u1.y) + c2 * bflo(u2.y) + c3 * bflo(u3.y)
                + c4s * bflo(u4.y) + c5 * bflo(u5.y) + c6 * bflo(u6.y) + c7 * bflo(u7.y);
            a3 += c0 * bfhi(u0.y) + c1 * bfhi(u1.y) + c2 * bfhi(u2.y) + c3 * bfhi(u3.y)
                + c4s * bfhi(u4.y) + c5 * bfhi(u5.y) + c6 * bfhi(u6.y) + c7 * bfhi(u7.y);
        } else {
            a0 += bflo(u0.x) + bflo(u1.x) + bflo(u2.x) + bflo(u3.x)
                + bflo(u4.x) + bflo(u5.x) + bflo(u6.x) + bflo(u7.x);
            a1 += bfhi(u0.x) + bfhi(u1.x) + bfhi(u2.x) + bfhi(u3.x)
                + bfhi(u4.x) + bfhi(u5.x) + bfhi(u6.x) + bfhi(u7.x);
            a2 += bflo(u0.y) + bflo(u1.y) + bflo(u2.y) + bflo(u3.y)
                + bflo(u4.y) + bflo(u5.y) + bflo(u6.y) + bflo(u7.y);
            a3 += bfhi(u0.y) + bfhi(u1.y) + bfhi(u2.y) + bfhi(u3.y)
                + bfhi(u4.y) + bfhi(u5.y) + bfhi(u6.y) + bfhi(u7.y);
        }
    }
    // ---- 8 neighbors / iter: 4 loads in flight per half
    for (; j + 8 <= cnt; j += 8) {
        int s0 = __shfl(myIdx, GSLOT(j + 0 + half));
        int s1 = __shfl(myIdx, GSLOT(j + 2 + half));
        int s2 = __shfl(myIdx, GSLOT(j + 4 + half));
        int s3 = __shfl(myIdx, GSLOT(j + 6 + half));
        uint2 u0 = *(const uint2*)&U[(size_t)s0 * 128 + c4];
        uint2 u1 = *(const uint2*)&U[(size_t)s1 * 128 + c4];
        uint2 u2 = *(const uint2*)&U[(size_t)s2 * 128 + c4];
        uint2 u3 = *(const uint2*)&U[(size_t)s3 * 128 + c4];
        if constexpr (SRCSCALE) {
            float c0 = __shfl(myDs, GSLOT(j + 0 + half));
            float c1 = __shfl(myDs, GSLOT(j + 2 + half));
            float c2 = __shfl(myDs, GSLOT(j + 4 + half));
            float c3 = __shfl(myDs, GSLOT(j + 6 + half));
            a0 += c0 * bflo(u0.x) + c1 * bflo(u1.x) + c2 * bflo(u2.x) + c3 * bflo(u3.x);
            a1 += c0 * bfhi(u0.x) + c1 * bfhi(u1.x) + c2 * bfhi(u2.x) + c3 * bfhi(u3.x);
            a2 += c0 * bflo(u0.y) + c1 * bflo(u1.y) + c2 * bflo(u2.y) + c3 * bflo(u3.y);
            a3 += c0 * bfhi(u0.y) + c1 * bfhi(u1.y) + c2 * bfhi(u2.y) + c3 * bfhi(u3.y);
        } else {
            a0 += bflo(u0.x) + bflo(u1.x) + bflo(u2.x) + bflo(u3.x);
            a1 += bfhi(u0.x) + bfhi(u1.x) + bfhi(u2.x) + bfhi(u3.x);
            a2 += bflo(u0.y) + bflo(u1.y) + bflo(u2.y) + bflo(u3.y);
            a3 += bfhi(u0.y) + bfhi(u1.y) + bfhi(u2.y) + bfhi(u3.y);
        }
    }
    // ---- 4 neighbors / iter: 2 loads in flight per half
    for (; j + 4 <= cnt; j += 4) {
        int s0 = __shfl(myIdx, GSLOT(j + 0 + half));
        int s1 = __shfl(myIdx, GSLOT(j + 2 + half));
        uint2 u0 = *(const uint2*)&U[(size_t)s0 * 128 + c4];
        uint2 u1 = *(const uint2*)&U[(size_t)s1 * 128 + c4];
        if constexpr (SRCSCALE) {
            float c0 = __shfl(myDs, GSLOT(j + 0 + half));
            float c1 = __shfl(myDs, GSLOT(j + 2 + half));
            a0 += c0 * bflo(u0.x) + c1 * bflo(u1.x);
            a1 += c0 * bfhi(u0.x) + c1 * bfhi(u1.x);
            a2 += c0 * bflo(u0.y) + c1 * bflo(u1.y);
            a3 += c0 * bfhi(u0.y) + c1 * bfhi(u1.y);
        } else {
            a0 += bflo(u0.x) + bflo(u1.x);
            a1 += bfhi(u0.x) + bfhi(u1.x);
            a2 += bflo(u0.y) + bflo(u1.y);
            a3 += bfhi(u0.y) + bfhi(u1.y);
        }
    }
    // ---- tail: 1..3 neighbors left (convergent clamped shuffle)
    for (; j < cnt; j += 2) {
        int jj = j + half;
        int vv = min(jj, cnt - 1);
        int sl = GSLOT(vv);
        int s  = __shfl(myIdx, sl);
        float sc = 1.f;
        if constexpr (SRCSCALE) sc = __shfl(myDs, sl);
        uint2 u = *(const uint2*)&U[(size_t)s * 128 + c4];
        if (jj < cnt) {
            a0 += sc * bflo(u.x); a1 += sc * bfhi(u.x);
            a2 += sc * bflo(u.y); a3 += sc * bfhi(u.y);
        }
    }
#undef GSLOT

    a0 += __shfl_xor(a0, 32);
    a1 += __shfl_xor(a1, 32);
    a2 += __shfl_xor(a2, 32);
    a3 += __shfl_xor(a3, 32);

    uint2 us = *(const uint2*)&U[(size_t)n * 128 + c4];
    float di = rsqrtf((float)degRaw + 1.0f);
    float selfs = SRCSCALE ? di : 1.0f;
    float4 bb = *(const float4*)&b[c4];
    float o0 = di * (a0 + selfs * bflo(us.x)) + bb.x;
    float o1 = di * (a1 + selfs * bfhi(us.x)) + bb.y;
    float o2 = di * (a2 + selfs * bflo(us.y)) + bb.z;
    float o3 = di * (a3 + selfs * bfhi(us.y)) + bb.w;
    if (half == 0) {
        ushort4 o;
        o.x = f2bf(o0); o.y = f2bf(o1); o.z = f2bf(o2); o.w = f2bf(o3);
        *(ushort4*)&Yb[(size_t)n * 128 + c4] = o;
    }
}

// ---------------------------------------------------------------------------
// gather64 with virtual compaction. VERBATIM round-10 (passing).
// ---------------------------------------------------------------------------
__global__ __launch_bounds__(256) void gather64_kernel(
    const ushort* __restrict__ csrf,
    const int* __restrict__ curA, const int* __restrict__ curB,
    const ushort* __restrict__ U, const float* __restrict__ b,
    float* __restrict__ Y)
{
    int t  = blockIdx.x * 256 + threadIdx.x;
    int n  = t >> 5;
    int l2 = t & 31;
    if (n >= NN) return;
    const int coff = l2 * 2;
    int dA = curA[n], dB = curB[n];
    int degRaw = dA + dB;
    int dA_c = min(dA, CAP);
    int dB_c = min(dB, CAP - dA_c);
    const int cnt = dA_c + dB_c;
    const int gap = CAP - cnt;
    int iA = (int)csrf[(size_t)n * CAP + l2];
    int iB = (int)csrf[(size_t)n * CAP + 32 + l2];
    float ax = 0.f, ay = 0.f;

#define GIDX(v, sv)                                            \
    int sv;                                                    \
    {                                                          \
        int _s = ((v) < dA_c) ? (v) : (v) + gap;               \
        int _l = __shfl(iA, _s & 31, 32);                      \
        int _h = __shfl(iB, _s & 31, 32);                      \
        sv = (_s < 32) ? _l : _h;                              \
    }

    int j = 0;
    for (; j + 8 <= cnt; j += 8) {
        GIDX(j + 0, s0) GIDX(j + 1, s1) GIDX(j + 2, s2) GIDX(j + 3, s3)
        GIDX(j + 4, s4) GIDX(j + 5, s5) GIDX(j + 6, s6) GIDX(j + 7, s7)
        unsigned u0 = *(const unsigned*)&U[(size_t)s0 * 64 + coff];
        unsigned u1 = *(const unsigned*)&U[(size_t)s1 * 64 + coff];
        unsigned u2 = *(const unsigned*)&U[(size_t)s2 * 64 + coff];
        unsigned u3 = *(const unsigned*)&U[(size_t)s3 * 64 + coff];
        unsigned u4 = *(const unsigned*)&U[(size_t)s4 * 64 + coff];
        unsigned u5 = *(const unsigned*)&U[(size_t)s5 * 64 + coff];
        unsigned u6 = *(const unsigned*)&U[(size_t)s6 * 64 + coff];
        unsigned u7 = *(const unsigned*)&U[(size_t)s7 * 64 + coff];
        ax += bflo(u0) + bflo(u1) + bflo(u2) + bflo(u3)
            + bflo(u4) + bflo(u5) + bflo(u6) + bflo(u7);
        ay += bfhi(u0) + bfhi(u1) + bfhi(u2) + bfhi(u3)
            + bfhi(u4) + bfhi(u5) + bfhi(u6) + bfhi(u7);
    }
    for (; j + 4 <= cnt; j += 4) {
        GIDX(j + 0, s0) GIDX(j + 1, s1) GIDX(j + 2, s2) GIDX(j + 3, s3)
        unsigned u0 = *(const unsigned*)&U[(size_t)s0 * 64 + coff];
        unsigned u1 = *(const unsigned*)&U[(size_t)s1 * 64 + coff];
        unsigned u2 = *(const unsigned*)&U[(size_t)s2 * 64 + coff];
        unsigned u3 = *(const unsigned*)&U[(size_t)s3 * 64 + coff];
        ax += bflo(u0) + bflo(u1) + bflo(u2) + bflo(u3);
        ay += bfhi(u0) + bfhi(u1) + bfhi(u2) + bfhi(u3);
    }
    for (; j < cnt; j++) {
        GIDX(j, s)
        unsigned u = *(const unsigned*)&U[(size_t)s * 64 + coff];
        ax += bflo(u); ay += bfhi(u);
    }
#undef GIDX

    unsigned us = *(const unsigned*)&U[(size_t)n * 64 + coff];
    float di = rsqrtf((float)degRaw + 1.0f);
    float ox = di * (ax + bflo(us)) + b[coff];
    float oy = di * (ay + bfhi(us)) + b[coff + 1];
    *(float2*)&Y[(size_t)n * 64 + coff] = make_float2(ox, oy);
}

// ---------------------------------------------------------------------------
// BN stats, round-0 structure + 4-row unrolled main loop (4 independent
// loads in flight per lane vs 1 — the same MLP lever that paid in the
// gathers, rounds 9/10). LDS/global atomic finale byte-identical (proven).
// ---------------------------------------------------------------------------
__global__ __launch_bounds__(256) void stats_kernel(const ushort* __restrict__ Yb,
                                                    float* __restrict__ sums,
                                                    float* __restrict__ sumsq)
{
    __shared__ float ssum[128], ssq[128];
    if (threadIdx.x < 128) { ssum[threadIdx.x] = 0.f; ssq[threadIdx.x] = 0.f; }
    __syncthreads();

    const int lane   = threadIdx.x & 63;
    const int gwave  = (blockIdx.x * 256 + threadIdx.x) >> 6;
    const int nWaves = gridDim.x * 4;
    const int coff   = lane * 2;

    float s0 = 0.f, s1 = 0.f, q0 = 0.f, q1 = 0.f;
    int row = gwave;
    for (; row + 3 * nWaves < NN; row += 4 * nWaves) {
        unsigned p0 = *(const unsigned*)&Yb[(size_t)(row)              * 128 + coff];
        unsigned p1 = *(const unsigned*)&Yb[(size_t)(row +     nWaves) * 128 + coff];
        unsigned p2 = *(const unsigned*)&Yb[(size_t)(row + 2 * nWaves) * 128 + coff];
        unsigned p3 = *(const unsigned*)&Yb[(size_t)(row + 3 * nWaves) * 128 + coff];
        float x0 = bflo(p0), y0 = bfhi(p0);
        float x1 = bflo(p1), y1 = bfhi(p1);
        float x2 = bflo(p2), y2 = bfhi(p2);
        float x3 = bflo(p3), y3 = bfhi(p3);
        s0 += x0 + x1 + x2 + x3;
        s1 += y0 + y1 + y2 + y3;
        q0 += x0 * x0 + x1 * x1 + x2 * x2 + x3 * x3;
        q1 += y0 * y0 + y1 * y1 + y2 * y2 + y3 * y3;
    }
    for (; row < NN; row += nWaves) {
        unsigned p = *(const unsigned*)&Yb[(size_t)row * 128 + coff];
        float yx = bflo(p), yy = bfhi(p);
        s0 += yx; q0 += yx * yx;
        s1 += yy; q1 += yy * yy;
    }
    atomicAdd(&ssum[coff], s0);     atomicAdd(&ssum[coff + 1], s1);
    atomicAdd(&ssq[coff], q0);      atomicAdd(&ssq[coff + 1], q1);
    __syncthreads();
    if (threadIdx.x < 128) {
        atomicAdd(&sums[threadIdx.x],  ssum[threadIdx.x]);
        atomicAdd(&sumsq[threadIdx.x], ssq[threadIdx.x]);
    }
}

// ---------------------------------------------------------------------------
extern "C" void kernel_launch(void* const* d_in, const int* in_sizes, int n_in,
                              void* d_out, int out_size, void* d_ws, size_t ws_size,
                              hipStream_t stream)
{
    const float* x   = (const float*)d_in[0];
    const int*   ei  = (const int*)d_in[1];
    const int*   src = ei;
    const int*   dst = ei + NE;
    const float* W1 = (const float*)d_in[2];  const float* b1 = (const float*)d_in[3];
    const float* W2 = (const float*)d_in[4];  const float* b2 = (const float*)d_in[5];
    const float* W3 = (const float*)d_in[6];  const float* b3 = (const float*)d_in[7];
    const float* W4 = (const float*)d_in[8];  const float* b4 = (const float*)d_in[9];
    const float* g1 = (const float*)d_in[10]; const float* be1 = (const float*)d_in[11];
    const float* g2 = (const float*)d_in[12]; const float* be2 = (const float*)d_in[13];
    const float* g3 = (const float*)d_in[14]; const float* be3 = (const float*)d_in[15];
    float* out = (float*)d_out;

    // workspace layout — BYTE-IDENTICAL to round-0/4/8/9/10 (FROZEN).
    char* wsb = (char*)d_ws;
    int*   curA   = (int*)wsb;                      // NN i
    int*   curB   = curA + NN;                      // NN i
    float* stats  = (float*)(curB + NN);            // 3 layers x 256 f
    ushort* Wt    = (ushort*)(stats + 768);         // 57344 us
    ushort* csrf  = Wt + 57344;                     // NN*64 us (6.4 MB)
    ushort* Yb    = csrf + (size_t)NN * CAP;        // NN*128 us (bf16 Y)
    ushort* U     = Yb + (size_t)NN * 128;          // NN*128 us (bf16 U)

    float* sums1 = stats;       float* sumsq1 = stats + 128;
    float* sums2 = stats + 256; float* sumsq2 = stats + 384;
    float* sums3 = stats + 512; float* sumsq3 = stats + 640;

    const ushort* Wt2 = Wt + 16384;
    const ushort* Wt3 = Wt + 32768;
    const ushort* Wt4 = Wt + 49152;

    const int gemmGrid   = (NN + 63) / 64;           // 782
    const int gathGrid   = (NN * 64 + 255) / 256;    // one wave per node
    const int gath64Grid = (NN * 32 + 255) / 256;    // half-wave per node

    // ---- prep + layer-1 GEMM fused
    hipMemsetAsync(curA, 0, 2 * NN * sizeof(int) + 768 * sizeof(float), stream);
    fused_prep_gemm1<<<FUSED_NB, 256, 0, stream>>>(src, dst, curA, curB, csrf,
                                                   W1, W2, W3, W4, Wt, x, U);

    // ---- Layer 1 (U unscaled -> gather applies dinv[src] per neighbor)
    gather128_kernel<true><<<gathGrid, 256, 0, stream>>>(csrf, curA, curB, U, b1, Yb);
    stats_kernel<<<512, 256, 0, stream>>>(Yb, sums1, sumsq1);

    // ---- Layer 2
    gemm_bf16_kernel<128, true><<<gemmGrid, 256, 0, stream>>>(Yb, Wt2, curA, curB, sums1, sumsq1, g1, be1, U);
    gather128_kernel<false><<<gathGrid, 256, 0, stream>>>(csrf, curA, curB, U, b2, Yb);
    stats_kernel<<<512, 256, 0, stream>>>(Yb, sums2, sumsq2);

    // ---- Layer 3
    gemm_bf16_kernel<128, true><<<gemmGrid, 256, 0, stream>>>(Yb, Wt3, curA, curB, sums2, sumsq2, g2, be2, U);
    gather128_kernel<false><<<gathGrid, 256, 0, stream>>>(csrf, curA, curB, U, b3, Yb);
    stats_kernel<<<512, 256, 0, stream>>>(Yb, sums3, sumsq3);

    // ---- Layer 4 (no BN stats; gather straight to d_out)
    gemm_bf16_kernel<64, true><<<gemmGrid, 256, 0, stream>>>(Yb, Wt4, curA, curB, sums3, sumsq3, g3, be3, U);
    gather64_kernel<<<gath64Grid, 256, 0, stream>>>(csrf, curA, curB, U, b4, out);
}